// Round 1
// baseline (719.140 us; speedup 1.0000x reference)
//
#include <hip/hip_runtime.h>
#include <math.h>

#define B_ROWS 131072
#define NE 2048
#define ZDIM 64
#define THREADS 256

// ---------------------------------------------------------------------------
// Kernel 0: precompute 0.5*|e_j|^2 for each codebook row.
// ---------------------------------------------------------------------------
__global__ void enorm_kernel(const float* __restrict__ E,
                             float* __restrict__ eNormHalf) {
    int j = blockIdx.x * blockDim.x + threadIdx.x;
    if (j < NE) {
        float s = 0.f;
#pragma unroll
        for (int d = 0; d < ZDIM; ++d) {
            float v = E[j * ZDIM + d];
            s = fmaf(v, v, s);
        }
        eNormHalf[j] = 0.5f * s;
    }
}

// ---------------------------------------------------------------------------
// Kernel 1: fused encoder -> argmin quantize -> decoder -> per-block partial
// sums of (l2 reconstruction, embedding loss).
// One thread = one row. z[64] lives in registers. The j-loop over the 2048
// codebook rows is wave-uniform, so E/eNormHalf loads are uniform -> scalar
// loads (SMEM pipe) overlapping the fp32 FMA stream.
// ---------------------------------------------------------------------------
__global__ __launch_bounds__(THREADS) void vqvae_main_kernel(
    const float* __restrict__ x,
    const float* __restrict__ W1, const float* __restrict__ b1,
    const float* __restrict__ W2, const float* __restrict__ b2,
    const float* __restrict__ W3, const float* __restrict__ b3,
    const float* __restrict__ W4, const float* __restrict__ b4,
    const float* __restrict__ W5, const float* __restrict__ b5,
    const float* __restrict__ W6, const float* __restrict__ b6,
    const float* __restrict__ W7, const float* __restrict__ b7,
    const float* __restrict__ W8, const float* __restrict__ b8,
    const float* __restrict__ E, const float* __restrict__ eNormHalf,
    float* __restrict__ partials /* [gridDim.x * 2] */) {

    const int row = blockIdx.x * blockDim.x + threadIdx.x;

    float l2 = 0.f;
    float emb = 0.f;

    if (row < B_ROWS) {
        // ---------------- load x ----------------
        float xin[5];
#pragma unroll
        for (int i = 0; i < 5; ++i) xin[i] = x[row * 5 + i];

        // ---------------- encoder ----------------
        float h1[16];
#pragma unroll
        for (int k = 0; k < 16; ++k) {
            float a = b1[k];
#pragma unroll
            for (int i = 0; i < 5; ++i) a = fmaf(xin[i], W1[i * 16 + k], a);
            h1[k] = fmaxf(a, 0.f);
        }
        float h2[32];
#pragma unroll
        for (int k = 0; k < 32; ++k) {
            float a = b2[k];
#pragma unroll
            for (int i = 0; i < 16; ++i) a = fmaf(h1[i], W2[i * 32 + k], a);
            h2[k] = fmaxf(a, 0.f);
        }
        float h3[16];
#pragma unroll
        for (int k = 0; k < 16; ++k) {
            float a = b3[k];
#pragma unroll
            for (int i = 0; i < 32; ++i) a = fmaf(h2[i], W3[i * 16 + k], a);
            h3[k] = fmaxf(a, 0.f);
        }
        float z[ZDIM];
#pragma unroll
        for (int k = 0; k < ZDIM; ++k) {
            float a = b4[k];
#pragma unroll
            for (int i = 0; i < 16; ++i) a = fmaf(h3[i], W4[i * 64 + k], a);
            z[k] = a;
        }

        // ---------------- argmin over codebook ----------------
        // d2_j = |z|^2 - 2 z.e_j + |e_j|^2 ; argmin d2 == argmax (z.e_j - 0.5|e_j|^2)
        // Strict '>' keeps the FIRST max -> matches jnp.argmin first-min tie-break.
        float best = -INFINITY;
        int bidx = 0;
        const float4* __restrict__ E4 = reinterpret_cast<const float4*>(E);
        for (int j = 0; j < NE; ++j) {
            float a0 = 0.f, a1 = 0.f, a2 = 0.f, a3 = 0.f;
#pragma unroll
            for (int q = 0; q < ZDIM / 4; ++q) {
                float4 e = E4[j * (ZDIM / 4) + q];
                a0 = fmaf(z[4 * q + 0], e.x, a0);
                a1 = fmaf(z[4 * q + 1], e.y, a1);
                a2 = fmaf(z[4 * q + 2], e.z, a2);
                a3 = fmaf(z[4 * q + 3], e.w, a3);
            }
            float score = ((a0 + a1) + (a2 + a3)) - eNormHalf[j];
            if (score > best) {
                best = score;
                bidx = j;
            }
        }

        // ---------------- gather z_q, embedding loss ----------------
        float zq[ZDIM];
#pragma unroll
        for (int d = 0; d < ZDIM; ++d) zq[d] = E[bidx * ZDIM + d];
#pragma unroll
        for (int d = 0; d < ZDIM; ++d) {
            float diff = z[d] - zq[d];
            emb = fmaf(diff, diff, emb);
        }
        emb *= 2.0f;  // embed_loss + BETA*commit_loss, BETA = 1

        // ---------------- decoder ----------------
        float g1[16];
#pragma unroll
        for (int k = 0; k < 16; ++k) {
            float a = b5[k];
#pragma unroll
            for (int i = 0; i < ZDIM; ++i) a = fmaf(zq[i], W5[i * 16 + k], a);
            g1[k] = fmaxf(a, 0.f);
        }
        float g2[32];
#pragma unroll
        for (int k = 0; k < 32; ++k) {
            float a = b6[k];
#pragma unroll
            for (int i = 0; i < 16; ++i) a = fmaf(g1[i], W6[i * 32 + k], a);
            g2[k] = fmaxf(a, 0.f);
        }
        float g3[16];
#pragma unroll
        for (int k = 0; k < 16; ++k) {
            float a = b7[k];
#pragma unroll
            for (int i = 0; i < 32; ++i) a = fmaf(g2[i], W7[i * 16 + k], a);
            g3[k] = fmaxf(a, 0.f);
        }
#pragma unroll
        for (int k = 0; k < 5; ++k) {
            float a = b8[k];
#pragma unroll
            for (int i = 0; i < 16; ++i) a = fmaf(g3[i], W8[i * 5 + k], a);
            float diff = xin[k] - a;
            l2 = fmaf(diff, diff, l2);
        }
    }

    // ---------------- block reduction (deterministic) ----------------
#pragma unroll
    for (int off = 32; off > 0; off >>= 1) {
        l2 += __shfl_down(l2, off);
        emb += __shfl_down(emb, off);
    }
    __shared__ float sl[THREADS / 64], se[THREADS / 64];
    const int wid = threadIdx.x >> 6;
    if ((threadIdx.x & 63) == 0) {
        sl[wid] = l2;
        se[wid] = emb;
    }
    __syncthreads();
    if (threadIdx.x == 0) {
        float L = 0.f, Em = 0.f;
#pragma unroll
        for (int w = 0; w < THREADS / 64; ++w) {
            L += sl[w];
            Em += se[w];
        }
        partials[2 * blockIdx.x + 0] = L;
        partials[2 * blockIdx.x + 1] = Em;
    }
}

// ---------------------------------------------------------------------------
// Kernel 2: reduce per-block partials (double accumulation) and emit the three
// scalar outputs: loss, -pxz, embedding_loss.
// ---------------------------------------------------------------------------
__global__ void finalize_kernel(const float* __restrict__ partials, int nblocks,
                                float* __restrict__ out) {
    __shared__ double sl[256], se[256];
    double a = 0.0, b = 0.0;
    for (int i = threadIdx.x; i < nblocks; i += 256) {
        a += (double)partials[2 * i + 0];
        b += (double)partials[2 * i + 1];
    }
    sl[threadIdx.x] = a;
    se[threadIdx.x] = b;
    __syncthreads();
    for (int s = 128; s > 0; s >>= 1) {
        if (threadIdx.x < s) {
            sl[threadIdx.x] += sl[threadIdx.x + s];
            se[threadIdx.x] += se[threadIdx.x + s];
        }
        __syncthreads();
    }
    if (threadIdx.x == 0) {
        double sum_l2 = sl[0];
        double embd = se[0];
        // pxz = -0.5*X_DIM*log(2*pi/MODEL_PRECISION) - 0.5*MODEL_PRECISION*sum_l2
        double c = -0.5 * 5.0 * log(2.0 * M_PI / 10.0);
        double neg_pxz = -(c - 5.0 * sum_l2);
        out[0] = (float)(neg_pxz + embd);  // loss
        out[1] = (float)neg_pxz;           // -pxz
        out[2] = (float)embd;              // embedding loss
    }
}

// ---------------------------------------------------------------------------
extern "C" void kernel_launch(void* const* d_in, const int* in_sizes, int n_in,
                              void* d_out, int out_size, void* d_ws,
                              size_t ws_size, hipStream_t stream) {
    const float* x = (const float*)d_in[0];
    const float* W1 = (const float*)d_in[1];
    const float* b1 = (const float*)d_in[2];
    const float* W2 = (const float*)d_in[3];
    const float* b2 = (const float*)d_in[4];
    const float* W3 = (const float*)d_in[5];
    const float* b3 = (const float*)d_in[6];
    const float* W4 = (const float*)d_in[7];
    const float* b4 = (const float*)d_in[8];
    const float* W5 = (const float*)d_in[9];
    const float* b5 = (const float*)d_in[10];
    const float* W6 = (const float*)d_in[11];
    const float* b6 = (const float*)d_in[12];
    const float* W7 = (const float*)d_in[13];
    const float* b7 = (const float*)d_in[14];
    const float* W8 = (const float*)d_in[15];
    const float* b8 = (const float*)d_in[16];
    const float* E = (const float*)d_in[17];

    float* eNormHalf = (float*)d_ws;                              // 2048 floats
    float* partials = (float*)((char*)d_ws + NE * sizeof(float)); // nblocks*2

    enorm_kernel<<<(NE + THREADS - 1) / THREADS, THREADS, 0, stream>>>(E, eNormHalf);

    const int nblocks = (B_ROWS + THREADS - 1) / THREADS;  // 512
    vqvae_main_kernel<<<nblocks, THREADS, 0, stream>>>(
        x, W1, b1, W2, b2, W3, b3, W4, b4, W5, b5, W6, b6, W7, b7, W8, b8, E,
        eNormHalf, partials);

    finalize_kernel<<<1, 256, 0, stream>>>(partials, nblocks, (float*)d_out);
}